// Round 1
// baseline (287.967 us; speedup 1.0000x reference)
//
#include <hip/hip_runtime.h>

typedef __attribute__((ext_vector_type(8))) short s16x8;   // 8 bf16 = 4 VGPR (MFMA A/B frag)
typedef __attribute__((ext_vector_type(4))) float f32x4;   // MFMA C/D frag

#define ALPHA_F 0.36787944117144233f
#define BETA_F  0.36787944117144233f
#define OMB_F   0.63212055882855767f   /* 1 - beta */

__device__ __forceinline__ unsigned short f2bf(float f){
  union { float f; unsigned int u; } v; v.f = f;
  unsigned int u = v.u;
  return (unsigned short)((u + 0x7FFFu + ((u >> 16) & 1u)) >> 16);  // RNE
}
__device__ __forceinline__ float bf2f(unsigned short s){
  union { unsigned int u; float f; } v; v.u = ((unsigned int)s) << 16;
  return v.f;
}

// ---- Kernel 0a: W (co,ci,3,3) fp32 -> Wr bf16 [pos9][cic4][co128][cil32] ----
__global__ __launch_bounds__(256) void reorder_w(const float* __restrict__ W,
                                                 unsigned short* __restrict__ Wr){
  int f = blockIdx.x * 256 + threadIdx.x;
  if (f >= 9*128*128) return;
  int cil = f & 31;
  int co  = (f >> 5) & 127;
  int cic = (f >> 12) & 3;
  int pos = f >> 14;
  int ci  = (cic << 5) | cil;
  Wr[f] = f2bf(W[(co*128 + ci)*9 + pos]);
}

// ---- Kernel 0b: x NCHW fp32 -> xcl channels-last bf16 [b][h][w][ci] ----
__global__ __launch_bounds__(256) void x_to_cl(const float* __restrict__ x,
                                               unsigned short* __restrict__ xcl){
  __shared__ unsigned short ls[128*113];
  int b = blockIdx.x / 112, h = blockIdx.x % 112;
  const float* xp = x + (size_t)b*1605632 + h*112;          // x[b][ci][h][w]
  for (int u = threadIdx.x; u < 128*112; u += 256){
    int ci = u / 112, w = u - ci*112;
    ls[ci*113 + w] = f2bf(xp[ci*12544 + w]);                // coalesced along w
  }
  __syncthreads();
  unsigned short* op = xcl + (size_t)(b*112 + h) * (112*128);
  for (int u = threadIdx.x; u < 112*64; u += 256){
    int pix = u >> 6, cp = u & 63;
    ushort2 v;
    v.x = ls[(2*cp  )*113 + pix];
    v.y = ls[(2*cp+1)*113 + pix];
    *(ushort2*)(op + pix*128 + 2*cp) = v;                   // coalesced along ci
  }
}

// ---- Kernel 1: fused implicit-GEMM conv3x3 (bf16 MFMA) + temporal IIR ----
// grid (7,14,16): bx=w-tile(16 cols), by=h-tile(8 rows), bz=batch.
// Block = 128 co x 128 pixels (8x16 patch). 4 waves, each 64co x 64pix (4x4 MFMA tiles).
__global__ __launch_bounds__(256, 2) void conv_lif(
    const unsigned short* __restrict__ xcl,
    const unsigned short* __restrict__ Wr,
    const float* __restrict__ bias,
    float* __restrict__ out)
{
  // staging: xs[10 rows][18 cols][32 ci] bf16 (11520 u16); epilogue aliases
  // ys[128 pix][132 (co,+4 pad)] bf16 (16896 u16) over the same buffer.
  __shared__ unsigned short sm[128*132];
  const int tid  = threadIdx.x;
  const int lane = tid & 63;
  const int wid  = tid >> 6;
  const int wm   = wid & 1;          // m-half (co 0..63 / 64..127)
  const int wn   = wid >> 1;         // n-half (rows 0..3 / 4..7)
  const int l15  = lane & 15;
  const int quad = lane >> 4;
  const int bz = blockIdx.z;
  const int h0 = blockIdx.y * 8, w0 = blockIdx.x * 16;

  f32x4 acc[4][4];
  #pragma unroll
  for (int i=0;i<4;i++)
    #pragma unroll
    for (int j=0;j<4;j++) acc[i][j] = (f32x4){0.f,0.f,0.f,0.f};

  const unsigned short* xb = xcl + (size_t)bz * (112*112*128);

  for (int cic = 0; cic < 4; ++cic){
    __syncthreads();                         // xs reads of prev iter done
    const int ci0 = cic << 5;
    #pragma unroll
    for (int it = 0; it < 6; ++it){
      int u = tid + it*256;                  // 180 pos * 8 quarters = 1440 units
      if (u < 1440){
        int posidx = u >> 3, cq = u & 7;
        int r = posidx / 18, c = posidx - r*18;
        int gh = h0 - 1 + r, gw = w0 - 1 + c;
        ushort4 val = make_ushort4(0,0,0,0);
        if (gh >= 0 && gh < 112 && gw >= 0 && gw < 112)
          val = *(const ushort4*)(xb + ((gh*112 + gw) << 7) + ci0 + (cq << 2));
        *(ushort4*)(sm + posidx*32 + (cq << 2)) = val;
      }
    }
    __syncthreads();
    #pragma unroll
    for (int pos = 0; pos < 9; ++pos){
      const int dh = pos/3, dw = pos - dh*3;
      // A-frags straight from L2-resident Wr: A[m=co=..+l15][k=ci=quad*8+j]
      const unsigned short* wb = Wr + (((pos<<2) + cic) << 12) + (wm<<11)
                                    + (l15<<5) + (quad<<3);
      s16x8 af[4];
      #pragma unroll
      for (int mt=0; mt<4; ++mt)
        af[mt] = *(const s16x8*)(wb + (mt<<9));
      #pragma unroll
      for (int nt=0; nt<4; ++nt){
        int rr = (wn<<2) + nt;               // pixel row in 8x16 patch
        const unsigned short* bp = sm + ((rr+dh)*18 + (l15+dw))*32 + (quad<<3);
        s16x8 bfr = *(const s16x8*)bp;       // ds_read_b128, B[k][n=l15]
        #pragma unroll
        for (int mt=0; mt<4; ++mt)
          acc[mt][nt] = __builtin_amdgcn_mfma_f32_16x16x32_bf16(af[mt], bfr, acc[mt][nt], 0, 0, 0);
      }
    }
  }

  __syncthreads();                           // done with xs; alias as ys
  // C/D layout: col(n=pix)=lane&15, row(m=co)=quad*4+reg
  #pragma unroll
  for (int mt=0; mt<4; ++mt){
    int cobase = (wm<<6) + (mt<<4) + (quad<<2);
    float4 bv = *(const float4*)(bias + cobase);
    #pragma unroll
    for (int nt=0; nt<4; ++nt){
      int pix = (((wn<<2)+nt)<<4) + l15;
      f32x4 a = acc[mt][nt];
      ushort4 w4;
      w4.x = f2bf(a.x + bv.x);
      w4.y = f2bf(a.y + bv.y);
      w4.z = f2bf(a.z + bv.z);
      w4.w = f2bf(a.w + bv.w);
      *(ushort4*)(sm + pix*132 + cobase) = w4;   // ys[pix][co], stride 132 kills conflicts
    }
  }
  __syncthreads();

  // temporal IIR along t=co per pixel: s=alpha*s+y; m=beta*m+(1-beta)*s
  if (tid < 128){
    int r = tid >> 4, c = tid & 15;
    float s = 0.f, m = 0.f;
    float* op = out + (size_t)bz*1605632 + (h0 + r)*112 + (w0 + c);
    const unsigned short* yr = sm + tid*132;
    #pragma unroll 8
    for (int t = 0; t < 128; ++t){
      float y = bf2f(yr[t]);
      s = ALPHA_F * s + y;
      m = BETA_F  * m + OMB_F * s;
      op[(size_t)t*12544] = m;                 // coalesced along w within each row
    }
  }
}

extern "C" void kernel_launch(void* const* d_in, const int* in_sizes, int n_in,
                              void* d_out, int out_size, void* d_ws, size_t ws_size,
                              hipStream_t stream){
  const float* x = (const float*)d_in[0];
  const float* W = (const float*)d_in[1];
  const float* b = (const float*)d_in[2];
  float* out = (float*)d_out;
  unsigned short* Wr  = (unsigned short*)d_ws;                       // 294912 B
  unsigned short* xcl = (unsigned short*)((char*)d_ws + (1 << 20));  // 51.4 MB
  reorder_w<<<576, 256, 0, stream>>>(W, Wr);
  x_to_cl<<<16*112, 256, 0, stream>>>(x, xcl);
  conv_lif<<<dim3(7, 14, 16), 256, 0, stream>>>(xcl, Wr, b, out);
}